// Round 1
// baseline (494.071 us; speedup 1.0000x reference)
//
#include <hip/hip_runtime.h>

#define HH 32      // hidden size
#define NB 16      // batches per block (one MFMA M-tile)
#define NT 512     // threads per block (8 waves)

typedef float f32x4 __attribute__((ext_vector_type(4)));
typedef __bf16 bf16x8 __attribute__((ext_vector_type(8)));

#if __has_builtin(__builtin_amdgcn_exp2f)
#define EXP2F(x) __builtin_amdgcn_exp2f(x)
#else
#define EXP2F(x) exp2f(x)
#endif
#if __has_builtin(__builtin_amdgcn_rcpf)
#define RCPF(x) __builtin_amdgcn_rcpf(x)
#else
#define RCPF(x) (1.0f / (x))
#endif

static __device__ __forceinline__ __bf16 f2bf(float f) {
  unsigned u = __builtin_bit_cast(unsigned, f);
  u += 0x7FFFu + ((u >> 16) & 1u);   // round-to-nearest-even
  unsigned short s = (unsigned short)(u >> 16);
  return __builtin_bit_cast(__bf16, s);
}
static __device__ __forceinline__ float bf2f(__bf16 b) {
  unsigned short s = __builtin_bit_cast(unsigned short, b);
  return __builtin_bit_cast(float, ((unsigned)s) << 16);
}
static __device__ __forceinline__ float sigm(float z) {
  return RCPF(1.0f + EXP2F(z * -1.44269504f));
}
static __device__ __forceinline__ float tanh_fast(float z) {
  // tanh(x) = 1 - 2/(1+exp(2x))
  return 1.0f - 2.0f * RCPF(1.0f + EXP2F(z * 2.88539008f));
}
static __device__ __forceinline__ f32x4 mfma16(bf16x8 a, bf16x8 b, f32x4 c) {
  return __builtin_amdgcn_mfma_f32_16x16x32_bf16(a, b, c, 0, 0, 0);
}

// Load B-fragment (hi/lo split) of row-major [128][32] f32 matrix for tile `tile`.
// B[k][col]: lane holds col = lane&15, k = (lane>>4)*8 + e  (self-consistent with A packing)
static __device__ __forceinline__ void load_wfrag(const float* __restrict__ M,
                                                  int tile, int lane,
                                                  bf16x8* hi, bf16x8* lo) {
  const int g = tile * 16 + (lane & 15);
  const int k0 = (lane >> 4) * 8;
  const float* p = M + g * HH + k0;
#pragma unroll
  for (int e = 0; e < 8; ++e) {
    float v = p[e];
    __bf16 h = f2bf(v);
    (*hi)[e] = h;
    (*lo)[e] = f2bf(v - bf2f(h));
  }
}

__global__ void __launch_bounds__(NT)
lstm_fused_kernel(const float* __restrict__ x,
                  const float* __restrict__ W1, const float* __restrict__ b1,
                  const float* __restrict__ Wih0, const float* __restrict__ Whh0,
                  const float* __restrict__ bih0, const float* __restrict__ bhh0,
                  const float* __restrict__ Wih1, const float* __restrict__ Whh1,
                  const float* __restrict__ bih1, const float* __restrict__ bhh1,
                  const float* __restrict__ W2, const float* __restrict__ b2,
                  float* __restrict__ out, int T)
{
  // A-fragment staging buffers (bf16 hi/lo), laid out so lane l reads 16B at l*16
  __shared__ __align__(16) __bf16 h0hi[512], h0lo[512];
  __shared__ __align__(16) __bf16 h1hi[512], h1lo[512];
  __shared__ __align__(16) __bf16 hinhi[512], hinlo[512];
  // gate exchange: [tile(8)][col(16)][row padded 17] f32
  __shared__ float glds[8 * 16 * 17];

  const int tid  = threadIdx.x;
  const int w    = tid >> 6;     // wave 0..7 -> owns gate tile w (gates [16w,16w+16))
  const int lane = tid & 63;
  const int ub   = tid & 15;     // update-role: batch within block
  const int uu   = tid >> 4;     // update-role: hidden unit 0..31
  const int b0   = blockIdx.x * NB;

  // ---- one-time setup ----
  bf16x8 whh0h, whh0l, wih0h, wih0l, wih1h, wih1l, whh1h, whh1l;
  load_wfrag(Whh0, w, lane, &whh0h, &whh0l);
  load_wfrag(Wih0, w, lane, &wih0h, &wih0l);
  load_wfrag(Wih1, w, lane, &wih1h, &wih1l);
  load_wfrag(Whh1, w, lane, &whh1h, &whh1l);

  const int gcol = w * 16 + (lane & 15);        // this lane's gate column (frag role)
  const float B0c = bih0[gcol] + bhh0[gcol];
  const float B1c = bih1[gcol] + bhh1[gcol];
  const float W1u = W1[uu];                      // I == 1
  const float b1u = b1[uu];

  // frag write position for update role: value h[b][u] -> fraglane f = b + 16*(u>>3), elem u&7
  const int fw = (ub + ((uu >> 3) << 4)) * 8 + (uu & 7);
  // gate LDS addressing
  const int gw_base = w * 272 + (lane & 15) * 17 + ((lane >> 4) << 2); // + q (q=0..3)
  const int gr_base = (uu >> 4) * 272 + (uu & 15) * 17 + ub;           // + 544*type

  h0hi[tid] = f2bf(0.0f); h0lo[tid] = f2bf(0.0f);
  h1hi[tid] = f2bf(0.0f); h1lo[tid] = f2bf(0.0f);

  float c0 = 0.0f, c1 = 0.0f, h0v = 0.0f, h1v = 0.0f;
  float xv = x[(b0 + ub) * T];
  const bool isg = ((w >> 1) == 2);  // tiles 4,5 hold the 'g' gate -> tanh
  __syncthreads();

  for (int t = 0; t < T; ++t) {
    // ---- P0: linear_1 + ReLU, stage as A-frag (update role) ----
    float hin = fmaxf(fmaf(xv, W1u, b1u), 0.0f);
    {
      __bf16 hh = f2bf(hin);
      hinhi[fw] = hh;
      hinlo[fw] = f2bf(hin - bf2f(hh));
    }
    if (t + 1 < T) xv = x[(b0 + ub) * T + t + 1];  // prefetch

    // ---- P1: recurrent MFMAs on OLD h frags (no barrier needed yet) ----
    bf16x8 a0h = *(const bf16x8*)(h0hi + lane * 8);
    bf16x8 a0l = *(const bf16x8*)(h0lo + lane * 8);
    bf16x8 a1h = *(const bf16x8*)(h1hi + lane * 8);
    bf16x8 a1l = *(const bf16x8*)(h1lo + lane * 8);
    f32x4 acc0 = {B0c, B0c, B0c, B0c};
    f32x4 acc1 = {B1c, B1c, B1c, B1c};
    acc0 = mfma16(a0h, whh0h, acc0);
    acc0 = mfma16(a0l, whh0h, acc0);
    acc0 = mfma16(a0h, whh0l, acc0);
    acc1 = mfma16(a1h, whh1h, acc1);
    acc1 = mfma16(a1l, whh1h, acc1);
    acc1 = mfma16(a1h, whh1l, acc1);
    __syncthreads();  // B1: hin frags visible
    bf16x8 aih = *(const bf16x8*)(hinhi + lane * 8);
    bf16x8 ail = *(const bf16x8*)(hinlo + lane * 8);
    acc0 = mfma16(aih, wih0h, acc0);
    acc0 = mfma16(ail, wih0h, acc0);
    acc0 = mfma16(aih, wih0l, acc0);

    // ---- P2: L0 gate activation (wave-uniform type), write to gate LDS ----
    if (isg) {
#pragma unroll
      for (int q = 0; q < 4; ++q) glds[gw_base + q] = tanh_fast(acc0[q]);
    } else {
#pragma unroll
      for (int q = 0; q < 4; ++q) glds[gw_base + q] = sigm(acc0[q]);
    }
    __syncthreads();  // B2

    // ---- P3: c0/h0 update (lane-local state), write new h0 frag ----
    {
      float iv = glds[gr_base];
      float fv = glds[gr_base + 544];
      float gv = glds[gr_base + 1088];
      float ov = glds[gr_base + 1632];
      c0 = fmaf(fv, c0, iv * gv);
      h0v = ov * tanh_fast(c0);
      __bf16 hb = f2bf(h0v);
      h0hi[fw] = hb;
      h0lo[fw] = f2bf(h0v - bf2f(hb));
    }
    __syncthreads();  // B3: new h0 frags visible; gate LDS free

    // ---- P4: L1 input-proj MFMAs on y0(t) = h0(t) ----
    bf16x8 ayh = *(const bf16x8*)(h0hi + lane * 8);
    bf16x8 ayl = *(const bf16x8*)(h0lo + lane * 8);
    acc1 = mfma16(ayh, wih1h, acc1);
    acc1 = mfma16(ayl, wih1h, acc1);
    acc1 = mfma16(ayh, wih1l, acc1);

    // ---- P5: L1 gate activation ----
    if (isg) {
#pragma unroll
      for (int q = 0; q < 4; ++q) glds[gw_base + q] = tanh_fast(acc1[q]);
    } else {
#pragma unroll
      for (int q = 0; q < 4; ++q) glds[gw_base + q] = sigm(acc1[q]);
    }
    __syncthreads();  // B4

    // ---- P6: c1/h1 update, write new h1 frag ----
    {
      float iv = glds[gr_base];
      float fv = glds[gr_base + 544];
      float gv = glds[gr_base + 1088];
      float ov = glds[gr_base + 1632];
      c1 = fmaf(fv, c1, iv * gv);
      h1v = ov * tanh_fast(c1);
      __bf16 hb = f2bf(h1v);
      h1hi[fw] = hb;
      h1lo[fw] = f2bf(h1v - bf2f(hb));
    }
    __syncthreads();  // B5: step complete
  }

  // ---- epilogue: out[b] = hf0[b,:]·W2[0:32] + hf1[b,:]·W2[32:64] + b2 ----
  float contrib = fmaf(h0v, W2[uu], h1v * W2[HH + uu]);
  glds[uu * 17 + ub] = contrib;   // reuse gate LDS as [u][b padded 17]
  __syncthreads();
  if (tid < NB) {
    float acc = b2[0];
#pragma unroll
    for (int u = 0; u < HH; ++u) acc += glds[u * 17 + tid];
    out[b0 + tid] = acc;
  }
}

extern "C" void kernel_launch(void* const* d_in, const int* in_sizes, int n_in,
                              void* d_out, int out_size, void* d_ws, size_t ws_size,
                              hipStream_t stream) {
  const float* x    = (const float*)d_in[0];
  const float* W1   = (const float*)d_in[1];
  const float* b1   = (const float*)d_in[2];
  const float* Wih0 = (const float*)d_in[3];
  const float* Whh0 = (const float*)d_in[4];
  const float* bih0 = (const float*)d_in[5];
  const float* bhh0 = (const float*)d_in[6];
  const float* Wih1 = (const float*)d_in[7];
  const float* Whh1 = (const float*)d_in[8];
  const float* bih1 = (const float*)d_in[9];
  const float* bhh1 = (const float*)d_in[10];
  const float* W2   = (const float*)d_in[11];
  const float* b2   = (const float*)d_in[12];

  const int B = out_size;                 // 4096
  const int I = in_sizes[1] / HH;         // 1
  const int T = in_sizes[0] / (B * I);    // 512
  const int blocks = B / NB;              // 256

  lstm_fused_kernel<<<blocks, NT, 0, stream>>>(
      x, W1, b1, Wih0, Whh0, bih0, bhh0, Wih1, Whh1, bih1, bhh1, W2, b2,
      (float*)d_out, T);
}

// Round 2
// 458.085 us; speedup vs baseline: 1.0786x; 1.0786x over previous
//
#include <hip/hip_runtime.h>

#define HH 32      // hidden size
#define NB 16      // batches per block (one MFMA M-tile)
#define NT 512     // threads per block (8 waves)
#define TT 512     // max T staged in LDS

typedef float f32x4 __attribute__((ext_vector_type(4)));
typedef __bf16 bf16x8 __attribute__((ext_vector_type(8)));
typedef unsigned int u32;
typedef unsigned short u16;
typedef u32 u32x4 __attribute__((ext_vector_type(4)));

#if __has_builtin(__builtin_amdgcn_exp2f)
#define EXP2F(x) __builtin_amdgcn_exp2f(x)
#else
#define EXP2F(x) exp2f(x)
#endif
#if __has_builtin(__builtin_amdgcn_rcpf)
#define RCPF(x) __builtin_amdgcn_rcpf(x)
#else
#define RCPF(x) (1.0f / (x))
#endif

static __device__ __forceinline__ float sigm(float z) {
  return RCPF(1.0f + EXP2F(z * -1.44269504f));
}
static __device__ __forceinline__ float tanh_fast(float z) {
  // tanh(z) = 2*sigm(2z) - 1
  return __builtin_fmaf(2.0f, RCPF(1.0f + EXP2F(z * -2.88539008f)), -1.0f);
}
static __device__ __forceinline__ f32x4 mfma16(bf16x8 a, bf16x8 b, f32x4 c) {
  return __builtin_amdgcn_mfma_f32_16x16x32_bf16(a, b, c, 0, 0, 0);
}

// ---- quad-lane exchange via DPP (quad_perm) ----
template<int CTRL>
static __device__ __forceinline__ float dppf(float x) {
#if __has_builtin(__builtin_amdgcn_mov_dpp)
  return __builtin_bit_cast(float,
      __builtin_amdgcn_mov_dpp(__builtin_bit_cast(int, x), CTRL, 0xF, 0xF, true));
#else
  const int m = (CTRL == 0xB1) ? 1 : (CTRL == 0x4E) ? 2 : 3;
  return __shfl_xor(x, m, 64);
#endif
}

// round-to-nearest-even f32 -> bf16 bits in the TOP 16 of a u32
static __device__ __forceinline__ u32 rne_hi(u32 b) {
  return (b + 0x7FFFu + ((b >> 16) & 1u)) & 0xFFFF0000u;
}
static __device__ __forceinline__ u32 pack_hi16(u32 a, u32 b) {
  // result = [b[31:16] : a[31:16]]
#if __has_builtin(__builtin_amdgcn_perm)
  return __builtin_amdgcn_perm(a, b, 0x03020706u);  // S0=a -> bytes6,7 ; S1=b -> bytes2,3
#else
  return (b & 0xFFFF0000u) | (a >> 16);
#endif
}

// split 8 f32 into (hi, lo) bf16x8 A/B-operand halves; hi is RNE-rounded,
// lo = exact remainder, truncated to bf16 (err ~2^-15 rel total).
static __device__ __forceinline__ void split8(const float f[8], bf16x8* hi, bf16x8* lo) {
  u32 r[8];
  float lof[8];
#pragma unroll
  for (int j = 0; j < 8; ++j) {
    u32 b = __builtin_bit_cast(u32, f[j]);
    r[j] = rne_hi(b);
    lof[j] = f[j] - __builtin_bit_cast(float, r[j]);  // exact
  }
  u32x4 hw, lw;
#pragma unroll
  for (int i = 0; i < 4; ++i) {
    hw[i] = pack_hi16(r[2 * i], r[2 * i + 1]);
    lw[i] = pack_hi16(__builtin_bit_cast(u32, lof[2 * i]),
                      __builtin_bit_cast(u32, lof[2 * i + 1]));
  }
  *hi = __builtin_bit_cast(bf16x8, hw);
  *lo = __builtin_bit_cast(bf16x8, lw);
}

// B-fragment of [4H][H] weight, gate-permuted: wave-tile col n -> gate row
// gi = (n&3)*H + 4*tile + (n>>2)   (type-major within quads)
// lane layout: col = lane&15, k = (lane>>4)*8 + e   (matches A packing; HW-verified r1)
static __device__ __forceinline__ void load_wfrag(const float* __restrict__ M,
                                                  int tile, int lane,
                                                  bf16x8* hi, bf16x8* lo) {
  const int n = lane & 15;
  const int gi = (n & 3) * HH + 4 * tile + (n >> 2);
  const int k0 = (lane >> 4) * 8;
  const float* p = M + gi * HH + k0;
  float f[8];
#pragma unroll
  for (int e = 0; e < 8; ++e) f[e] = p[e];
  split8(f, hi, lo);
}

// in-quad gather of (i,f,g,o) for batch p=lane&3, then activation + c/h update.
// Input: z[j] = pre-activation for batch_group j, this lane's gate type (=lane&3).
static __device__ __forceinline__ float gate_update(f32x4 z, bool q1, bool q2, float& c) {
  const float A0 = z[0], A1 = z[1], A2 = z[2], A3 = z[3];
  // s_m = z[p^m] (element the XOR-m partner needs); shared cndmask inner pairs
  const float L13 = q1 ? A0 : A1;
  const float H13 = q1 ? A2 : A3;
  const float L02 = q1 ? A1 : A0;
  const float H02 = q1 ? A3 : A2;
  const float s1 = q2 ? H13 : L13;
  const float s3 = q2 ? L13 : H13;
  const float s0 = q2 ? H02 : L02;
  const float s2 = q2 ? L02 : H02;
  const float g1 = dppf<0xB1>(s1);   // quad_perm [1,0,3,2] : xor 1
  const float g2 = dppf<0x4E>(s2);   // quad_perm [2,3,0,1] : xor 2
  const float g3 = dppf<0x1B>(s3);   // quad_perm [3,2,1,0] : xor 3
  // z[type t][batch p] = (t==p) ? s0 : g_{t^p}
  const float zi = q2 ? (q1 ? g3 : g2) : (q1 ? g1 : s0);
  const float zf = q2 ? (q1 ? g2 : g3) : (q1 ? s0 : g1);
  const float zg = q2 ? (q1 ? g1 : s0) : (q1 ? g3 : g2);
  const float zo = q2 ? (q1 ? s0 : g1) : (q1 ? g2 : g3);
  const float iv = sigm(zi), fv = sigm(zf), ov = sigm(zo);
  const float gv = tanh_fast(zg);
  c = __builtin_fmaf(fv, c, iv * gv);
  return ov * tanh_fast(c);
}

static __device__ __forceinline__ void store_h(u16* hiA, u16* loA, int fw, float h) {
  const u32 b = __builtin_bit_cast(u32, h);
  const u32 r = rne_hi(b);
  hiA[fw] = (u16)(r >> 16);
  const float lof = h - __builtin_bit_cast(float, r);
  loA[fw] = (u16)(__builtin_bit_cast(u32, lof) >> 16);
}

__global__ void __launch_bounds__(NT)
lstm_fused_v2(const float* __restrict__ x,
              const float* __restrict__ W1, const float* __restrict__ b1,
              const float* __restrict__ Wih0, const float* __restrict__ Whh0,
              const float* __restrict__ bih0, const float* __restrict__ bhh0,
              const float* __restrict__ Wih1, const float* __restrict__ Whh1,
              const float* __restrict__ bih1, const float* __restrict__ bhh1,
              const float* __restrict__ W2, const float* __restrict__ b2,
              float* __restrict__ out, int T)
{
  // double-buffered A-fragments (bf16 hi/lo as u16), linear: lane reads 16B at lane*16
  __shared__ __align__(16) u16 h0hi[2][NB * HH], h0lo[2][NB * HH];
  __shared__ __align__(16) u16 h1hi[2][NB * HH], h1lo[2][NB * HH];
  // x staged transposed: xT[t*NB + b]  (per-step read = 16 consecutive words, bcast x4)
  __shared__ __align__(16) float xT[TT * NB];   // 32 KB

  const int tid  = threadIdx.x;
  const int w    = tid >> 6;
  const int lane = tid & 63;
  const int n    = lane & 15;
  const int b0   = blockIdx.x * NB;

  // ---- weights (one-time, register-resident B-frags) ----
  bf16x8 whh0h, whh0l, wih0h, wih0l, wih1h, wih1l, whh1h, whh1l;
  load_wfrag(Whh0, w, lane, &whh0h, &whh0l);
  load_wfrag(Wih0, w, lane, &wih0h, &wih0l);
  load_wfrag(Wih1, w, lane, &wih1h, &wih1l);
  load_wfrag(Whh1, w, lane, &whh1h, &whh1l);

  const int gi  = (n & 3) * HH + 4 * w + (n >> 2);
  const float B0c = bih0[gi] + bhh0[gi];
  const float B1c = bih1[gi] + bhh1[gi];

  // hin role (A-frag): row b = n, k-units u = (lane>>4)*8 + e
  float W1v[8], b1v[8];
#pragma unroll
  for (int e = 0; e < 8; ++e) {
    const int u = (lane >> 4) * 8 + e;
    W1v[e] = W1[u];
    b1v[e] = b1[u];
  }

  // update role: this lane owns (batch bq, unit uu)
  const int bq = ((lane >> 4) << 2) + (lane & 3);
  const int uu = 4 * w + (n >> 2);
  const int fw = (bq + ((uu >> 3) << 4)) * 8 + (uu & 7);
  const bool q1 = (lane & 1), q2 = (lane & 2);

  // ---- stage x into LDS (transposed), zero-init h frag bufs ----
  {
    const int row = tid >> 5;              // 0..15
    const int c0i = (tid & 31) * 16;       // 16 timesteps per thread
    if (c0i + 16 <= T) {
      const float* xp = x + (size_t)(b0 + row) * T + c0i;
#pragma unroll
      for (int j = 0; j < 16; j += 4) {
        float4 v = *(const float4*)(xp + j);
        xT[(c0i + j + 0) * NB + row] = v.x;
        xT[(c0i + j + 1) * NB + row] = v.y;
        xT[(c0i + j + 2) * NB + row] = v.z;
        xT[(c0i + j + 3) * NB + row] = v.w;
      }
    }
  }
  h0hi[0][tid] = 0; h0hi[1][tid] = 0; h0lo[0][tid] = 0; h0lo[1][tid] = 0;
  h1hi[0][tid] = 0; h1hi[1][tid] = 0; h1lo[0][tid] = 0; h1lo[1][tid] = 0;

  float c0 = 0.0f, c1 = 0.0f, h0v = 0.0f, h1v = 0.0f;
  __syncthreads();

  // ---- pipelined main loop: iter k does L0(t=k) and L1(t=k-1); ONE barrier ----
  for (int k = 0; k <= T; ++k) {
    const int wb = k & 1, rb = wb ^ 1;
    // h0(k-1) from buf rb; h1(k-2) from buf wb
    const bf16x8 a0h = *(const bf16x8*)&h0hi[rb][lane * 8];
    const bf16x8 a0l = *(const bf16x8*)&h0lo[rb][lane * 8];
    const bf16x8 a1h = *(const bf16x8*)&h1hi[wb][lane * 8];
    const bf16x8 a1l = *(const bf16x8*)&h1lo[wb][lane * 8];

    if (k < T) {                                    // ---- L0(t=k) ----
      const float xv = xT[k * NB + n];
      float hf[8];
#pragma unroll
      for (int e = 0; e < 8; ++e)
        hf[e] = fmaxf(__builtin_fmaf(xv, W1v[e], b1v[e]), 0.0f);
      bf16x8 aih, ail;
      split8(hf, &aih, &ail);

      f32x4 r0 = {B0c, B0c, B0c, B0c};
      r0 = mfma16(a0h, whh0h, r0);
      r0 = mfma16(a0l, whh0h, r0);
      r0 = mfma16(a0h, whh0l, r0);
      f32x4 i0 = {0.f, 0.f, 0.f, 0.f};
      i0 = mfma16(aih, wih0h, i0);
      i0 = mfma16(ail, wih0h, i0);
      i0 = mfma16(aih, wih0l, i0);
      const f32x4 z0 = r0 + i0;

      h0v = gate_update(z0, q1, q2, c0);
      store_h(h0hi[wb], h0lo[wb], fw, h0v);         // h0(k) -> buf k&1
    }

    if (k > 0) {                                    // ---- L1(t=k-1) ----
      f32x4 r1 = {B1c, B1c, B1c, B1c};
      r1 = mfma16(a1h, whh1h, r1);
      r1 = mfma16(a1l, whh1h, r1);
      r1 = mfma16(a1h, whh1l, r1);
      f32x4 i1 = {0.f, 0.f, 0.f, 0.f};
      i1 = mfma16(a0h, wih1h, i1);                  // input = h0(k-1)
      i1 = mfma16(a0l, wih1h, i1);
      i1 = mfma16(a0h, wih1l, i1);
      const f32x4 z1 = r1 + i1;

      h1v = gate_update(z1, q1, q2, c1);
      store_h(h1hi[rb], h1lo[rb], fw, h1v);         // h1(k-1) -> buf (k-1)&1
    }
    __syncthreads();
  }

  // ---- epilogue: out[b] = sum_u h0f[b,u]*W2[u] + h1f[b,u]*W2[H+u] + b2 ----
  float* red = xT;  // reuse (safe: loop finished behind the final barrier)
  red[uu * NB + bq] = __builtin_fmaf(h0v, W2[uu], h1v * W2[HH + uu]);
  __syncthreads();
  if (tid < NB) {
    float acc = b2[0];
#pragma unroll
    for (int u = 0; u < HH; ++u) acc += red[u * NB + tid];
    out[b0 + tid] = acc;
  }
}

extern "C" void kernel_launch(void* const* d_in, const int* in_sizes, int n_in,
                              void* d_out, int out_size, void* d_ws, size_t ws_size,
                              hipStream_t stream) {
  const float* x    = (const float*)d_in[0];
  const float* W1   = (const float*)d_in[1];
  const float* b1   = (const float*)d_in[2];
  const float* Wih0 = (const float*)d_in[3];
  const float* Whh0 = (const float*)d_in[4];
  const float* bih0 = (const float*)d_in[5];
  const float* bhh0 = (const float*)d_in[6];
  const float* Wih1 = (const float*)d_in[7];
  const float* Whh1 = (const float*)d_in[8];
  const float* bih1 = (const float*)d_in[9];
  const float* bhh1 = (const float*)d_in[10];
  const float* W2   = (const float*)d_in[11];
  const float* b2   = (const float*)d_in[12];

  const int B = out_size;                 // 4096
  const int I = in_sizes[1] / HH;         // 1
  const int T = in_sizes[0] / (B * I);    // 512
  const int blocks = B / NB;              // 256

  lstm_fused_v2<<<blocks, NT, 0, stream>>>(
      x, W1, b1, Wih0, Whh0, bih0, bhh0, Wih1, Whh1, bih1, bhh1, W2, b2,
      (float*)d_out, T);
}

// Round 3
// 262.933 us; speedup vs baseline: 1.8791x; 1.7422x over previous
//
#include <hip/hip_runtime.h>

#define HH 32      // hidden size
#define NB 16      // batches per block (one MFMA N-tile now)
#define NT 512     // threads per block (8 waves)
#define TT 512     // max T staged in LDS

typedef float f32x4 __attribute__((ext_vector_type(4)));
typedef __bf16 bf16x8 __attribute__((ext_vector_type(8)));
typedef unsigned int u32;
typedef unsigned short u16;
typedef u32 u32x4 __attribute__((ext_vector_type(4)));

#if __has_builtin(__builtin_amdgcn_exp2f)
#define EXP2F(x) __builtin_amdgcn_exp2f(x)
#else
#define EXP2F(x) exp2f(x)
#endif
#if __has_builtin(__builtin_amdgcn_rcpf)
#define RCPF(x) __builtin_amdgcn_rcpf(x)
#else
#define RCPF(x) (1.0f / (x))
#endif

static __device__ __forceinline__ float sigm(float z) {
  return RCPF(1.0f + EXP2F(z * -1.44269504f));
}
static __device__ __forceinline__ float tanh_fast(float z) {
  return __builtin_fmaf(2.0f, RCPF(1.0f + EXP2F(z * -2.88539008f)), -1.0f);
}
// A = weight fragment, B = state fragment
static __device__ __forceinline__ f32x4 mfma16(bf16x8 a, bf16x8 b, f32x4 c) {
  return __builtin_amdgcn_mfma_f32_16x16x32_bf16(a, b, c, 0, 0, 0);
}

// round-to-nearest-even f32 -> bf16 bits in TOP 16, rest zeroed
static __device__ __forceinline__ u32 rne_hi(u32 b) {
  return (b + 0x7FFFu + ((b >> 16) & 1u)) & 0xFFFF0000u;
}
static __device__ __forceinline__ u32 pack_hi16(u32 a, u32 b) {
  // result = [b[31:16] : a[31:16]]
#if __has_builtin(__builtin_amdgcn_perm)
  return __builtin_amdgcn_perm(a, b, 0x03020706u);
#else
  return (b & 0xFFFF0000u) | (a >> 16);
#endif
}
static __device__ __forceinline__ void split8(const float f[8], bf16x8* hi, bf16x8* lo) {
  u32 r[8];
  float lof[8];
#pragma unroll
  for (int j = 0; j < 8; ++j) {
    u32 b = __builtin_bit_cast(u32, f[j]);
    r[j] = rne_hi(b);
    lof[j] = f[j] - __builtin_bit_cast(float, r[j]);  // exact
  }
  u32x4 hw, lw;
#pragma unroll
  for (int i = 0; i < 4; ++i) {
    hw[i] = pack_hi16(r[2 * i], r[2 * i + 1]);
    lw[i] = pack_hi16(__builtin_bit_cast(u32, lof[2 * i]),
                      __builtin_bit_cast(u32, lof[2 * i + 1]));
  }
  *hi = __builtin_bit_cast(bf16x8, hw);
  *lo = __builtin_bit_cast(bf16x8, lw);
}

// A-fragment of [4H][H] weight for wave `tile`, gate-permuted:
// A row m -> weight row gi = (m&3)*H + 4*tile + (m>>2)  (m&3 = gate type)
// lane layout: m = lane&15, k = (lane>>4)*8 + e  (HW-verified packing, r1/r2)
static __device__ __forceinline__ void load_wfrag(const float* __restrict__ M,
                                                  int tile, int lane,
                                                  bf16x8* hi, bf16x8* lo) {
  const int m = lane & 15;
  const int gi = (m & 3) * HH + 4 * tile + (m >> 2);
  const int k0 = (lane >> 4) * 8;
  const float* p = M + gi * HH + k0;
  float f[8];
#pragma unroll
  for (int e = 0; e < 8; ++e) f[e] = p[e];
  split8(f, hi, lo);
}

static __device__ __forceinline__ void store_h(u16* hiA, u16* loA, int fw, float h) {
  const u32 b = __builtin_bit_cast(u32, h);
  const u32 r = rne_hi(b);
  hiA[fw] = (u16)(r >> 16);
  const float lof = h - __builtin_bit_cast(float, r);
  loA[fw] = (u16)(__builtin_bit_cast(u32, lof) >> 16);
}

__global__ void __launch_bounds__(NT)
lstm_fused_v3(const float* __restrict__ x,
              const float* __restrict__ W1, const float* __restrict__ b1,
              const float* __restrict__ Wih0, const float* __restrict__ Whh0,
              const float* __restrict__ bih0, const float* __restrict__ bhh0,
              const float* __restrict__ Wih1, const float* __restrict__ Whh1,
              const float* __restrict__ bih1, const float* __restrict__ bhh1,
              const float* __restrict__ W2, const float* __restrict__ b2,
              float* __restrict__ out, int T)
{
  // state B-fragments (bf16 hi/lo as u16), double-buffered; lane reads 16B at lane*16
  __shared__ __align__(16) u16 h0hi[2][NB * HH], h0lo[2][NB * HH];
  __shared__ __align__(16) u16 h1hi[2][NB * HH], h1lo[2][NB * HH];
  __shared__ __align__(16) u16 hxhi[2][NB * HH], hxlo[2][NB * HH];  // hin
  __shared__ __align__(16) float xT[TT * NB];   // x transposed [t][b]

  const int tid  = threadIdx.x;
  const int w    = tid >> 6;
  const int lane = tid & 63;
  const int ub   = lane & 15;          // owned batch (D col)
  const int G    = lane >> 4;
  const int uu   = 4 * w + G;          // owned unit (D row group)
  const int b0   = blockIdx.x * NB;

  // ---- weights as register-resident A-frags ----
  bf16x8 whh0h, whh0l, wih0h, wih0l, wih1h, wih1l, whh1h, whh1l;
  load_wfrag(Whh0, w, lane, &whh0h, &whh0l);
  load_wfrag(Wih0, w, lane, &wih0h, &wih0l);
  load_wfrag(Wih1, w, lane, &wih1h, &wih1l);
  load_wfrag(Whh1, w, lane, &whh1h, &whh1l);

  // per-lane gate biases: reg q = gate type q of unit uu
  f32x4 B0c, B1c;
#pragma unroll
  for (int q = 0; q < 4; ++q) {
    B0c[q] = bih0[q * HH + uu] + bhh0[q * HH + uu];
    B1c[q] = bih1[q * HH + uu] + bhh1[q * HH + uu];
  }
  const float W1u = W1[uu];
  const float b1u = b1[uu];

  // B-frag store slot for value [b=ub][k=uu]
  const int fw  = (ub + ((uu >> 3) << 4)) * 8 + (uu & 7);
  const int frd = lane * 8;            // u16 index of this lane's 16B frag read

  // ---- stage x transposed into LDS ----
  {
    const int row = tid >> 5;              // 0..15
    const int c0i = (tid & 31) * 16;       // 16 timesteps per thread
    if (c0i + 16 <= T) {
      const float* xp = x + (size_t)(b0 + row) * T + c0i;
#pragma unroll
      for (int j = 0; j < 16; j += 4) {
        float4 v = *(const float4*)(xp + j);
        xT[(c0i + j + 0) * NB + row] = v.x;
        xT[(c0i + j + 1) * NB + row] = v.y;
        xT[(c0i + j + 2) * NB + row] = v.z;
        xT[(c0i + j + 3) * NB + row] = v.w;
      }
    }
  }
  // zero-init state frags (both parities)
  h0hi[0][tid] = 0; h0hi[1][tid] = 0; h0lo[0][tid] = 0; h0lo[1][tid] = 0;
  h1hi[0][tid] = 0; h1hi[1][tid] = 0; h1lo[0][tid] = 0; h1lo[1][tid] = 0;
  // hin(0) cooperatively: one element per thread
  {
    const float hv = fmaxf(__builtin_fmaf(x[(size_t)(b0 + ub) * T], W1u, b1u), 0.0f);
    const u32 bb = __builtin_bit_cast(u32, hv);
    const u32 rr = rne_hi(bb);
    hxhi[0][fw] = (u16)(rr >> 16);
    const float lf = hv - __builtin_bit_cast(float, rr);
    hxlo[0][fw] = (u16)(__builtin_bit_cast(u32, lf) >> 16);
  }
  float c0 = 0.0f, c1 = 0.0f, h0v = 0.0f, h1v = 0.0f;
  __syncthreads();

// One pipeline step: iter k does L0(t=k), L1(t=k-1), hin(k+1).
// WB = k&1 (compile-time). Single barrier at the end.
#define STEP(kk, WB, DO_L0, DO_L1, DO_HIN)                                   \
  {                                                                          \
    const int RB = (WB) ^ 1;                                                 \
    const bf16x8 a0h = *(const bf16x8*)&h0hi[RB][frd];                       \
    const bf16x8 a0l = *(const bf16x8*)&h0lo[RB][frd];                       \
    bf16x8 a1h, a1l, axh, axl;                                               \
    if (DO_L1) { a1h = *(const bf16x8*)&h1hi[WB][frd];                       \
                 a1l = *(const bf16x8*)&h1lo[WB][frd]; }                     \
    if (DO_L0) { axh = *(const bf16x8*)&hxhi[WB][frd];                       \
                 axl = *(const bf16x8*)&hxlo[WB][frd]; }                     \
    if (DO_HIN) {  /* hin(kk+1), one element per thread, into buf RB */      \
      const float xv = xT[((kk) + 1) * NB + ub];                             \
      const float hv = fmaxf(__builtin_fmaf(xv, W1u, b1u), 0.0f);            \
      const u32 bb = __builtin_bit_cast(u32, hv);                            \
      const u32 rr = rne_hi(bb);                                             \
      hxhi[RB][fw] = (u16)(rr >> 16);                                        \
      const float lf = hv - __builtin_bit_cast(float, rr);                   \
      hxlo[RB][fw] = (u16)(__builtin_bit_cast(u32, lf) >> 16);               \
    }                                                                        \
    if (DO_L0) {                                                             \
      f32x4 z = B0c;                                                         \
      z = mfma16(whh0h, a0h, z); z = mfma16(whh0h, a0l, z);                  \
      z = mfma16(whh0l, a0h, z);                                             \
      z = mfma16(wih0h, axh, z); z = mfma16(wih0h, axl, z);                  \
      z = mfma16(wih0l, axh, z);                                             \
      const float iv = sigm(z[0]), fv = sigm(z[1]);                          \
      const float gv = tanh_fast(z[2]), ov = sigm(z[3]);                     \
      c0 = __builtin_fmaf(fv, c0, iv * gv);                                  \
      h0v = ov * tanh_fast(c0);                                              \
      store_h(h0hi[WB], h0lo[WB], fw, h0v);                                  \
    }                                                                        \
    if (DO_L1) {                                                             \
      f32x4 z = B1c;                                                         \
      z = mfma16(whh1h, a1h, z); z = mfma16(whh1h, a1l, z);                  \
      z = mfma16(whh1l, a1h, z);                                             \
      z = mfma16(wih1h, a0h, z); z = mfma16(wih1h, a0l, z);                  \
      z = mfma16(wih1l, a0h, z);                                             \
      const float iv = sigm(z[0]), fv = sigm(z[1]);                          \
      const float gv = tanh_fast(z[2]), ov = sigm(z[3]);                     \
      c1 = __builtin_fmaf(fv, c1, iv * gv);                                  \
      h1v = ov * tanh_fast(c1);                                              \
      store_h(h1hi[RB], h1lo[RB], fw, h1v);                                  \
    }                                                                        \
    __syncthreads();                                                         \
  }

  STEP(0, 0, true, false, true);                  // k=0: L0 only
  for (int kk = 1; kk + 1 < T; kk += 2) {         // k = 1..T-2 in parity pairs
    STEP(kk, 1, true, true, true);
    STEP(kk + 1, 0, true, true, true);
  }
  STEP(T - 1, 1, true, true, false);              // k=T-1 (odd): no hin(T)
  STEP(T, 0, false, true, false);                 // k=T: L1 only

#undef STEP

  // ---- epilogue: out[b] = sum_u h0f[b,u]*W2[u] + h1f[b,u]*W2[H+u] + b2 ----
  xT[uu * NB + ub] = __builtin_fmaf(h0v, W2[uu], h1v * W2[HH + uu]);
  __syncthreads();
  if (tid < NB) {
    float acc = b2[0];
#pragma unroll
    for (int u = 0; u < HH; ++u) acc += xT[u * NB + tid];
    out[b0 + tid] = acc;
  }
}

extern "C" void kernel_launch(void* const* d_in, const int* in_sizes, int n_in,
                              void* d_out, int out_size, void* d_ws, size_t ws_size,
                              hipStream_t stream) {
  const float* x    = (const float*)d_in[0];
  const float* W1   = (const float*)d_in[1];
  const float* b1   = (const float*)d_in[2];
  const float* Wih0 = (const float*)d_in[3];
  const float* Whh0 = (const float*)d_in[4];
  const float* bih0 = (const float*)d_in[5];
  const float* bhh0 = (const float*)d_in[6];
  const float* Wih1 = (const float*)d_in[7];
  const float* Whh1 = (const float*)d_in[8];
  const float* bih1 = (const float*)d_in[9];
  const float* bhh1 = (const float*)d_in[10];
  const float* W2   = (const float*)d_in[11];
  const float* b2   = (const float*)d_in[12];

  const int B = out_size;                 // 4096
  const int I = in_sizes[1] / HH;         // 1
  const int T = in_sizes[0] / (B * I);    // 512
  const int blocks = B / NB;              // 256

  lstm_fused_v3<<<blocks, NT, 0, stream>>>(
      x, W1, b1, Wih0, Whh0, bih0, bhh0, Wih1, Whh1, bih1, bhh1, W2, b2,
      (float*)d_out, T);
}